// Round 2
// baseline (455.842 us; speedup 1.0000x reference)
//
#include <hip/hip_runtime.h>

// Problem constants
#define NB 128
#define NC 256
#define HX 31
#define WX 31
#define HZ 7
#define WZ 7
#define HC 25          // corr spatial (31-7+1)
#define WC 25
#define HO 23          // head output spatial (25-3+1)
#define WO 23
#define CHUNKS 4
#define CPB (NC / CHUNKS)    // 64 channels per block
#define GRP 7                // channels per group iteration
#define TPC 36               // threads per channel (6x6 tile grid)
#define XROW 36              // padded LDS row stride (16B-aligned rows)
#define XCH (HX * XROW)      // 1116 floats per channel of x in LDS
#define ZCH 52               // padded z (13 float4)
#define WCH 48               // padded weights (12 float4): 9 heat + 4*9 reg + 3 pad

#define HEAT_SZ (NB * HO * WO)       // 67712
#define REG_SZ  (NB * 4 * HO * WO)   // 270848
#define OUT_TOTAL (HEAT_SZ + REG_SZ) // 338560

// Writes bias into d_out (harness poisons d_out with 0xAA before every launch).
__global__ void init_out_kernel(float* __restrict__ out,
                                const float* __restrict__ heat_b,
                                const float* __restrict__ reg_b) {
    int i = blockIdx.x * 256 + threadIdx.x;
    if (i >= OUT_TOTAL) return;
    if (i < HEAT_SZ) {
        out[i] = heat_b[0];
    } else {
        int j = i - HEAT_SZ;
        int o = (j / (HO * WO)) & 3;
        out[i] = reg_b[o];
    }
}

// Register-fused depthwise xcorr + dual 3x3 conv heads.
// Thread = (channel-in-group, 4x4 output tile). Corr 6x6 patch computed in
// registers per channel (1.64x redundant FLOPs, zero corr LDS traffic),
// conv accumulated register-only into 80 persistent accumulators.
__launch_bounds__(256, 2)
__global__ void fused_head_kernel(const float* __restrict__ xf,
                                  const float* __restrict__ zf,
                                  const float* __restrict__ hw,
                                  const float* __restrict__ rw,
                                  float* __restrict__ out) {
    __shared__ __align__(16) float xs[GRP * XCH];   // 31.2 KB
    __shared__ __align__(16) float zs[GRP * ZCH];   // 1.5 KB
    __shared__ __align__(16) float ws[GRP * WCH];   // 1.3 KB

    const int tid = threadIdx.x;
    const int n = blockIdx.x >> 2;
    const int chunk = blockIdx.x & 3;
    const int cbase = chunk * CPB;

    const int cl = tid / TPC;          // channel-in-group (7 -> idle lanes 252-255)
    const int tt = tid % TPC;
    const int tr = tt / 6, tc = tt % 6;
    const int i0 = 4 * tr, j0 = 4 * tc;     // output tile origin
    const int th = (tr < 5) ? 4 : 3;        // tile height (rows 20..22 for tr=5)
    const int tw = (tc < 5) ? 4 : 3;

    // persistent accumulators: 16 px x 5 heads
    float accH[4][4];
    float accR[4][4][4];   // [o][oy][ox]
    #pragma unroll
    for (int oy = 0; oy < 4; ++oy)
        #pragma unroll
        for (int ox = 0; ox < 4; ++ox) {
            accH[oy][ox] = 0.f;
            #pragma unroll
            for (int o = 0; o < 4; ++o) accR[o][oy][ox] = 0.f;
        }

    const float* xn = xf + ((size_t)n * NC + cbase) * (HX * WX);
    const float* zn = zf + ((size_t)n * NC + cbase) * (HZ * WZ);

    for (int g0 = 0; g0 < CPB; g0 += GRP) {
        const int G = (CPB - g0) < GRP ? (CPB - g0) : GRP;   // 7 x9, then 1

        // ---- stage x: global -> LDS (padded rows, coalesced b32 loads) ----
        for (int idx = tid; idx < G * (HX * WX); idx += 256) {
            int ch = idx / (HX * WX);
            int r = idx - ch * (HX * WX);
            int row = r / WX;
            int col = r - row * WX;
            xs[ch * XCH + row * XROW + col] = xn[(size_t)(g0 + ch) * (HX * WX) + r];
        }
        // ---- stage z ----
        for (int idx = tid; idx < G * 49; idx += 256) {
            int ch = idx / 49;
            int q = idx - ch * 49;
            zs[ch * ZCH + q] = zn[(size_t)(g0 + ch) * 49 + q];
        }
        // ---- stage weights (45 per channel, padded to 48) ----
        for (int idx = tid; idx < G * 45; idx += 256) {
            int ch = idx / 45;
            int j = idx - ch * 45;
            int c = cbase + g0 + ch;
            float v;
            if (j < 9) {
                v = hw[c * 9 + j];
            } else {
                int o = (j - 9) / 9;
                int jj = (j - 9) - o * 9;
                v = rw[((size_t)o * NC + c) * 9 + jj];
            }
            ws[ch * WCH + j] = v;
        }
        __syncthreads();

        if (cl < G) {
            // ---- z template into registers (broadcast b128 reads) ----
            float zr[52];
            {
                const float4* zp = (const float4*)(zs + cl * ZCH);
                #pragma unroll
                for (int q = 0; q < 13; ++q) {
                    float4 t = zp[q];
                    zr[q * 4 + 0] = t.x; zr[q * 4 + 1] = t.y;
                    zr[q * 4 + 2] = t.z; zr[q * 4 + 3] = t.w;
                }
            }
            // ---- corr 6x6 patch in registers ----
            float cacc[6][6];
            #pragma unroll
            for (int r = 0; r < 6; ++r)
                #pragma unroll
                for (int b = 0; b < 6; ++b) cacc[r][b] = 0.f;

            const float* xb = xs + cl * XCH + j0;
            #pragma unroll
            for (int rl = 0; rl < 12; ++rl) {
                int row = i0 + rl;
                if (row > 30) row = 30;   // tr=5,rl=11: garbage -> unused cacc[5]
                const float* rp = xb + row * XROW;
                float4 a0 = *(const float4*)(rp);
                float4 a1 = *(const float4*)(rp + 4);
                float4 a2 = *(const float4*)(rp + 8);
                float xr[12] = {a0.x, a0.y, a0.z, a0.w,
                                a1.x, a1.y, a1.z, a1.w,
                                a2.x, a2.y, a2.z, a2.w};
                #pragma unroll
                for (int u = 0; u < 7; ++u) {
                    const int r = rl - u;
                    if (r >= 0 && r < 6) {   // folds at compile time
                        #pragma unroll
                        for (int v = 0; v < 7; ++v) {
                            const float zv = zr[u * 7 + v];
                            #pragma unroll
                            for (int b = 0; b < 6; ++b)
                                cacc[r][b] = fmaf(zv, xr[b + v], cacc[r][b]);
                        }
                    }
                }
            }
            // ---- conv heads: register-only, 720 FMA ----
            float w[48];
            {
                const float4* wp = (const float4*)(ws + cl * WCH);
                #pragma unroll
                for (int q = 0; q < 12; ++q) {
                    float4 t = wp[q];
                    w[q * 4 + 0] = t.x; w[q * 4 + 1] = t.y;
                    w[q * 4 + 2] = t.z; w[q * 4 + 3] = t.w;
                }
            }
            #pragma unroll
            for (int oy = 0; oy < 4; ++oy)
                #pragma unroll
                for (int ox = 0; ox < 4; ++ox)
                    #pragma unroll
                    for (int dy = 0; dy < 3; ++dy)
                        #pragma unroll
                        for (int dx = 0; dx < 3; ++dx) {
                            const float cv = cacc[oy + dy][ox + dx];
                            const int k = dy * 3 + dx;
                            accH[oy][ox]    = fmaf(cv, w[k],          accH[oy][ox]);
                            accR[0][oy][ox] = fmaf(cv, w[9 + k],      accR[0][oy][ox]);
                            accR[1][oy][ox] = fmaf(cv, w[18 + k],     accR[1][oy][ox]);
                            accR[2][oy][ox] = fmaf(cv, w[27 + k],     accR[2][oy][ox]);
                            accR[3][oy][ox] = fmaf(cv, w[36 + k],     accR[3][oy][ox]);
                        }
        }
        __syncthreads();
    }

    // ---- epilogue: atomic accumulate (bias pre-written by init kernel) ----
    if (cl < GRP) {
        float* outH = out + n * (HO * WO);
        float* outR = out + HEAT_SZ + (size_t)n * 4 * (HO * WO);
        #pragma unroll
        for (int oy = 0; oy < 4; ++oy) {
            if (oy < th) {
                #pragma unroll
                for (int ox = 0; ox < 4; ++ox) {
                    if (ox < tw) {
                        const int p = (i0 + oy) * WO + (j0 + ox);
                        atomicAdd(&outH[p], accH[oy][ox]);
                        #pragma unroll
                        for (int o = 0; o < 4; ++o)
                            atomicAdd(&outR[o * (HO * WO) + p], accR[o][oy][ox]);
                    }
                }
            }
        }
    }
}

extern "C" void kernel_launch(void* const* d_in, const int* in_sizes, int n_in,
                              void* d_out, int out_size, void* d_ws, size_t ws_size,
                              hipStream_t stream) {
    const float* x_f    = (const float*)d_in[0];
    const float* z_f    = (const float*)d_in[1];
    const float* heat_w = (const float*)d_in[2];
    const float* heat_b = (const float*)d_in[3];
    const float* reg_w  = (const float*)d_in[4];
    const float* reg_b  = (const float*)d_in[5];
    float* out = (float*)d_out;

    init_out_kernel<<<(OUT_TOTAL + 255) / 256, 256, 0, stream>>>(out, heat_b, reg_b);
    fused_head_kernel<<<NB * CHUNKS, 256, 0, stream>>>(x_f, z_f, heat_w, reg_w, out);
}

// Round 3
// 248.363 us; speedup vs baseline: 1.8354x; 1.8354x over previous
//
#include <hip/hip_runtime.h>

// Problem constants
#define NB 128
#define NC 256
#define HX 31
#define WX 31
#define HC 25          // corr spatial (31-7+1)
#define WC 25
#define HO 23          // head output spatial (25-3+1)
#define WO 23
#define CHUNKS 8       // channel chunks per batch item -> 1024 blocks, 4/CU
#define CPB (NC / CHUNKS)    // 32 channels per block
#define GRP 10               // channels per group iteration (25 threads each)
#define ZCH 56               // z: 7 rows * 8 stride (16B-aligned rows)
#define WCH 48               // weights: 45 padded to 48 (12 float4)
#define CCH (HC * WC)        // 625

#define HEAT_SZ (NB * HO * WO)       // 67712
#define REG_SZ  (NB * 4 * HO * WO)   // 270848
#define OUT_TOTAL (HEAT_SZ + REG_SZ) // 338560

// unaligned-capable float4 (x rows start at arbitrary dword offsets)
typedef float f4v __attribute__((ext_vector_type(4), aligned(4)));

// Writes bias into d_out (harness poisons d_out with 0xAA before every launch).
__global__ void init_out_kernel(float* __restrict__ out,
                                const float* __restrict__ heat_b,
                                const float* __restrict__ reg_b) {
    int i = blockIdx.x * 256 + threadIdx.x;
    if (i >= OUT_TOTAL) return;
    if (i < HEAT_SZ) {
        out[i] = heat_b[0];
    } else {
        int j = i - HEAT_SZ;
        int o = (j / (HO * WO)) & 3;
        out[i] = reg_b[o];
    }
}

// Exact-corr fused kernel, v3: x read from global (L2/L3), corr in regs ->
// cs in LDS, conv heads gather from cs. 4 blocks/CU (VGPR<=128, LDS ~34KB).
__launch_bounds__(256, 4)
__global__ void fused_head_kernel(const float* __restrict__ xf,
                                  const float* __restrict__ zf,
                                  const float* __restrict__ hw,
                                  const float* __restrict__ rw,
                                  float* __restrict__ out) {
    __shared__ __align__(16) float cs[GRP * CCH];   // 25.0 KB
    __shared__ __align__(16) float zs[GRP * ZCH];   // 2.2 KB
    __shared__ __align__(16) float ws[CPB * WCH];   // 6.0 KB

    const int tid = threadIdx.x;
    const int n = blockIdx.x >> 3;
    const int chunk = blockIdx.x & 7;
    const int cbase = chunk * CPB;

    // corr mapping: 25 threads/channel, each owns an exact 5x5 corr tile
    const int cl = tid / 25;               // channel-in-group (>=G -> idle)
    const int tt = tid % 25;
    const int tr = tt / 5, tc = tt % 5;
    const int i0 = tr * 5, j0 = tc * 5;

    // conv mapping: thread owns pixels tid, tid+256, (tid+512 if tid<17)
    const int p0 = tid;
    const int p1 = tid + 256;
    const int p2 = tid + 512;
    const int oy0 = p0 / 23, ox0 = p0 - oy0 * 23;
    const int oy1 = p1 / 23, ox1 = p1 - oy1 * 23;
    const int oy2 = p2 / 23, ox2 = p2 - oy2 * 23;
    const int off0 = oy0 * WC + ox0;
    const int off1 = oy1 * WC + ox1;
    const int off2 = (tid < 17) ? (oy2 * WC + ox2) : 0;

    float accH0 = 0.f, accH1 = 0.f, accH2 = 0.f;
    float accR0[4] = {0.f, 0.f, 0.f, 0.f};
    float accR1[4] = {0.f, 0.f, 0.f, 0.f};
    float accR2[4] = {0.f, 0.f, 0.f, 0.f};

    const float* xn = xf + ((size_t)n * NC + cbase) * (HX * WX);
    const float* zn = zf + ((size_t)n * NC + cbase) * 49;

    // ---- stage all 32 channels' head weights once (broadcast reads later) ----
    for (int idx = tid; idx < CPB * 45; idx += 256) {
        int ch = idx / 45, j = idx - ch * 45;
        int c = cbase + ch;
        float v;
        if (j < 9) {
            v = hw[c * 9 + j];
        } else {
            int o = (j - 9) / 9;
            int jj = (j - 9) - o * 9;
            v = rw[((size_t)o * NC + c) * 9 + jj];
        }
        ws[ch * WCH + j] = v;
    }

    for (int g0 = 0; g0 < CPB; g0 += GRP) {
        const int G = (CPB - g0) < GRP ? (CPB - g0) : GRP;   // 10,10,10,2

        // ---- stage z, rows padded to stride 8 for aligned b128 reads ----
        for (int idx = tid; idx < G * 49; idx += 256) {
            int ch = idx / 49, q = idx - ch * 49;
            int u = q / 7, v = q - u * 7;
            zs[ch * ZCH + u * 8 + v] = zn[(size_t)(g0 + ch) * 49 + q];
        }
        __syncthreads();

        // ---- exact corr: x rows from global, pipelined one row ahead ----
        if (cl < G) {
            const float* xb = xn + (size_t)(g0 + cl) * (HX * WX) + i0 * WX + j0;
            const float* zb = zs + cl * ZCH;

            float cacc[5][5];
            #pragma unroll
            for (int r = 0; r < 5; ++r)
                #pragma unroll
                for (int b = 0; b < 5; ++b) cacc[r][b] = 0.f;

            f4v c0 = *(const f4v*)(xb);
            f4v c1 = *(const f4v*)(xb + 4);
            f4v c2 = *(const f4v*)(xb + 7);   // cols j0+7..j0+10 (max col 30)

            #pragma unroll
            for (int rl = 0; rl < 11; ++rl) {
                f4v n0, n1, n2;
                if (rl < 10) {
                    const float* rp = xb + (rl + 1) * WX;
                    n0 = *(const f4v*)(rp);
                    n1 = *(const f4v*)(rp + 4);
                    n2 = *(const f4v*)(rp + 7);
                }
                const float xr[11] = {c0.x, c0.y, c0.z, c0.w,
                                      c1.x, c1.y, c1.z, c1.w,
                                      c2.y, c2.z, c2.w};
                #pragma unroll
                for (int u = 0; u < 7; ++u) {
                    const int r = rl - u;           // folds at compile time
                    if (r >= 0 && r < 5) {
                        f4v za = *(const f4v*)(zb + u * 8);      // broadcast
                        f4v zc = *(const f4v*)(zb + u * 8 + 4);
                        const float zz[7] = {za.x, za.y, za.z, za.w,
                                             zc.x, zc.y, zc.z};
                        #pragma unroll
                        for (int v = 0; v < 7; ++v)
                            #pragma unroll
                            for (int b = 0; b < 5; ++b)
                                cacc[r][b] = fmaf(zz[v], xr[b + v], cacc[r][b]);
                    }
                }
                if (rl < 10) { c0 = n0; c1 = n1; c2 = n2; }
            }
            float* cb = cs + cl * CCH + i0 * WC + j0;
            #pragma unroll
            for (int r = 0; r < 5; ++r)
                #pragma unroll
                for (int b = 0; b < 5; ++b) cb[r * WC + b] = cacc[r][b];
        }
        __syncthreads();

        // ---- conv heads over this group's channels ----
        for (int clc = 0; clc < G; ++clc) {
            float w[48];
            {
                const f4v* wp = (const f4v*)(ws + (size_t)(g0 + clc) * WCH);
                #pragma unroll
                for (int q = 0; q < 12; ++q) {     // broadcast b128
                    f4v t = wp[q];
                    w[q * 4 + 0] = t.x; w[q * 4 + 1] = t.y;
                    w[q * 4 + 2] = t.z; w[q * 4 + 3] = t.w;
                }
            }
            const float* cc = cs + clc * CCH;

            {   // pixel p0
                const float* base = cc + off0;
                #pragma unroll
                for (int dy = 0; dy < 3; ++dy)
                    #pragma unroll
                    for (int dx = 0; dx < 3; ++dx) {
                        const float cv = base[dy * WC + dx];
                        const int k = dy * 3 + dx;
                        accH0    = fmaf(cv, w[k],      accH0);
                        accR0[0] = fmaf(cv, w[9 + k],  accR0[0]);
                        accR0[1] = fmaf(cv, w[18 + k], accR0[1]);
                        accR0[2] = fmaf(cv, w[27 + k], accR0[2]);
                        accR0[3] = fmaf(cv, w[36 + k], accR0[3]);
                    }
            }
            {   // pixel p1
                const float* base = cc + off1;
                #pragma unroll
                for (int dy = 0; dy < 3; ++dy)
                    #pragma unroll
                    for (int dx = 0; dx < 3; ++dx) {
                        const float cv = base[dy * WC + dx];
                        const int k = dy * 3 + dx;
                        accH1    = fmaf(cv, w[k],      accH1);
                        accR1[0] = fmaf(cv, w[9 + k],  accR1[0]);
                        accR1[1] = fmaf(cv, w[18 + k], accR1[1]);
                        accR1[2] = fmaf(cv, w[27 + k], accR1[2]);
                        accR1[3] = fmaf(cv, w[36 + k], accR1[3]);
                    }
            }
            if (tid < 17) {   // pixel p2
                const float* base = cc + off2;
                #pragma unroll
                for (int dy = 0; dy < 3; ++dy)
                    #pragma unroll
                    for (int dx = 0; dx < 3; ++dx) {
                        const float cv = base[dy * WC + dx];
                        const int k = dy * 3 + dx;
                        accH2    = fmaf(cv, w[k],      accH2);
                        accR2[0] = fmaf(cv, w[9 + k],  accR2[0]);
                        accR2[1] = fmaf(cv, w[18 + k], accR2[1]);
                        accR2[2] = fmaf(cv, w[27 + k], accR2[2]);
                        accR2[3] = fmaf(cv, w[36 + k], accR2[3]);
                    }
            }
        }
        __syncthreads();
    }

    // ---- epilogue: atomic accumulate (bias pre-written by init kernel) ----
    float* outH = out + n * (HO * WO);
    float* outR = out + HEAT_SZ + (size_t)n * 4 * (HO * WO);

    atomicAdd(&outH[p0], accH0);
    #pragma unroll
    for (int o = 0; o < 4; ++o)
        atomicAdd(&outR[o * (HO * WO) + p0], accR0[o]);

    atomicAdd(&outH[p1], accH1);
    #pragma unroll
    for (int o = 0; o < 4; ++o)
        atomicAdd(&outR[o * (HO * WO) + p1], accR1[o]);

    if (tid < 17) {
        atomicAdd(&outH[p2], accH2);
        #pragma unroll
        for (int o = 0; o < 4; ++o)
            atomicAdd(&outR[o * (HO * WO) + p2], accR2[o]);
    }
}

extern "C" void kernel_launch(void* const* d_in, const int* in_sizes, int n_in,
                              void* d_out, int out_size, void* d_ws, size_t ws_size,
                              hipStream_t stream) {
    const float* x_f    = (const float*)d_in[0];
    const float* z_f    = (const float*)d_in[1];
    const float* heat_w = (const float*)d_in[2];
    const float* heat_b = (const float*)d_in[3];
    const float* reg_w  = (const float*)d_in[4];
    const float* reg_b  = (const float*)d_in[5];
    float* out = (float*)d_out;

    init_out_kernel<<<(OUT_TOTAL + 255) / 256, 256, 0, stream>>>(out, heat_b, reg_b);
    fused_head_kernel<<<NB * CHUNKS, 256, 0, stream>>>(x_f, z_f, heat_w, reg_w, out);
}